// Round 2
// baseline (635.974 us; speedup 1.0000x reference)
//
#include <hip/hip_runtime.h>
#include <math.h>

#define D 1024
#define NROW 128
#define PANEL 16
#define NPANELS 8
#define NTHREADS 1024
#define XP 1028                       // Xc row pitch (floats): +16B rotates banks per row
#define SMP 16                        // Smb row pitch (floats)
#define MAXPREV ((NPANELS - 1) * PANEL)

typedef __attribute__((ext_vector_type(8))) short short8;
typedef __attribute__((ext_vector_type(4))) float floatx4;

__device__ __forceinline__ unsigned short f2bf(float f) {  // RNE f32 -> bf16 (inputs finite)
  unsigned int u = __builtin_bit_cast(unsigned int, f);
  u += 0x7fffu + ((u >> 16) & 1u);
  return (unsigned short)(u >> 16);
}

// Classical block Gram-Schmidt: the reference projects ORIGINAL x_i onto all previous
// q_j (row i untouched until step i), so all cross-panel corrections for panel k are
// independent of each other -> one fused dots phase + one fused update phase per panel.
__global__ __launch_bounds__(NTHREADS, 4) void gs_kernel(const float* __restrict__ xg_all,
                                                         float* __restrict__ qg_all) {
  __shared__ __align__(16) float Xc[PANEL][XP];        // ~66 KB fp32 master panel
  __shared__ __align__(16) float Smb[MAXPREV][SMP];    // 7 KB: scaled S rows (all prev chunks)
  __shared__ __align__(16) float Scr[4096];            // 16 KB: MFMA partials / csum partials
  __shared__ float Gm[PANEL][PANEL];
  __shared__ float LT[PANEL][PANEL];                   // LT[r][m] = L[m][r]
  __shared__ float rinv[NROW];

  const int t = threadIdx.x;
  const int lane = t & 63;
  const int w = t >> 6;
  const int wb = w << 6;               // wave-owned 64-column strip base
  const size_t off = (size_t)blockIdx.x * (NROW * D);
  const float* xg = xg_all + off;
  float* qg = qg_all + off;

  float csum = 0.0f;   // column t sum of squares
  float4 xr[4];        // X-panel register prefetch

  // ---- prologue: stage panel 0 (contiguous conflict-free mapping), prefetch panel 1 ----
  {
    const float4* s = (const float4*)xg;
#pragma unroll
    for (int r = 0; r < 4; ++r) xr[r] = s[r * 1024 + t];
#pragma unroll
    for (int r = 0; r < 4; ++r) {
      const int idx = r * 1024 + t;
      *(float4*)&Xc[idx >> 8][(idx & 255) << 2] = xr[r];
    }
    const float4* s1 = (const float4*)(xg + PANEL * D);
#pragma unroll
    for (int r = 0; r < 4; ++r) xr[r] = s1[r * 1024 + t];
  }
  __syncthreads();

  for (int k = 0; k < NPANELS; ++k) {
    const int i0 = k * PANEL;

    // ---- A: fused dots. Wave w < k computes S_w = Q_w * X_k^T (16x16, full K=1024).
    //      Q from global (L2/L3-hot; this block wrote it). No cross-wave reduce.
    if (w < k) {
      const int m = lane & 15;    // A row (Q row within chunk) and B row (X row within panel)
      const int kb = lane >> 4;   // K sub-block
      const float* qrow = qg + (size_t)(w * PANEL + m) * D;
      floatx4 acc = {0.f, 0.f, 0.f, 0.f};
#pragma unroll 4
      for (int s = 0; s < 32; ++s) {
        const int kk = s * 32 + kb * 8;
        const float4 qlo = *(const float4*)(qrow + kk);
        const float4 qhi = *(const float4*)(qrow + kk + 4);
        const float4 xlo = *(const float4*)&Xc[m][kk];
        const float4 xhi = *(const float4*)&Xc[m][kk + 4];
        short8 a, b;
        a[0] = (short)f2bf(qlo.x); a[1] = (short)f2bf(qlo.y);
        a[2] = (short)f2bf(qlo.z); a[3] = (short)f2bf(qlo.w);
        a[4] = (short)f2bf(qhi.x); a[5] = (short)f2bf(qhi.y);
        a[6] = (short)f2bf(qhi.z); a[7] = (short)f2bf(qhi.w);
        b[0] = (short)f2bf(xlo.x); b[1] = (short)f2bf(xlo.y);
        b[2] = (short)f2bf(xlo.z); b[3] = (short)f2bf(xlo.w);
        b[4] = (short)f2bf(xhi.x); b[5] = (short)f2bf(xhi.y);
        b[6] = (short)f2bf(xhi.z); b[7] = (short)f2bf(xhi.w);
        acc = __builtin_amdgcn_mfma_f32_16x16x32_bf16(a, b, acc, 0, 0, 0);
      }
      // C/D map: col = lane&15 (=p), row = (lane>>4)*4 + reg (=j within chunk)
#pragma unroll
      for (int r = 0; r < 4; ++r) {
        const int j = w * PANEL + kb * 4 + r;
        Smb[j][m] = acc[r] * rinv[j];
      }
    }
    __syncthreads();

    // ---- B: fused fp32 update X_k -= sum_j Smb[j][p] * Q[j][d]; wave-local columns.
    //      Q float4 from global: 4 lane-groups share each address -> coalesced broadcast.
    if (k > 0) {
      const int p0 = (lane >> 4) << 2;
      const int d0 = wb + ((lane & 15) << 2);
      float4 x0 = *(const float4*)&Xc[p0 + 0][d0];
      float4 x1 = *(const float4*)&Xc[p0 + 1][d0];
      float4 x2 = *(const float4*)&Xc[p0 + 2][d0];
      float4 x3 = *(const float4*)&Xc[p0 + 3][d0];
#pragma unroll 8
      for (int j = 0; j < i0; ++j) {
        const float4 qv = *(const float4*)(qg + (size_t)j * D + d0);
        const float4 sv = *(const float4*)&Smb[j][p0];   // wave-uniform broadcast
        x0.x -= sv.x * qv.x; x0.y -= sv.x * qv.y; x0.z -= sv.x * qv.z; x0.w -= sv.x * qv.w;
        x1.x -= sv.y * qv.x; x1.y -= sv.y * qv.y; x1.z -= sv.y * qv.z; x1.w -= sv.y * qv.w;
        x2.x -= sv.z * qv.x; x2.y -= sv.z * qv.y; x2.z -= sv.z * qv.z; x2.w -= sv.z * qv.w;
        x3.x -= sv.w * qv.x; x3.y -= sv.w * qv.y; x3.z -= sv.w * qv.z; x3.w -= sv.w * qv.w;
      }
      *(float4*)&Xc[p0 + 0][d0] = x0;
      *(float4*)&Xc[p0 + 1][d0] = x1;
      *(float4*)&Xc[p0 + 2][d0] = x2;
      *(float4*)&Xc[p0 + 3][d0] = x3;
    }
    // no barrier: GRAM reads only this wave's columns (same-wave LDS ordering)

    // ---- C: within-panel Gram via MFMA; wave w covers K in [64w, 64w+64) ----
    {
      const int m = lane & 15;
      const int kb = lane >> 4;
      floatx4 acc = {0.f, 0.f, 0.f, 0.f};
#pragma unroll
      for (int h = 0; h < 2; ++h) {
        const int kk = wb + kb * 8 + h * 32;
        const float4 xlo = *(const float4*)&Xc[m][kk];
        const float4 xhi = *(const float4*)&Xc[m][kk + 4];
        short8 a;
        a[0] = (short)f2bf(xlo.x); a[1] = (short)f2bf(xlo.y);
        a[2] = (short)f2bf(xlo.z); a[3] = (short)f2bf(xlo.w);
        a[4] = (short)f2bf(xhi.x); a[5] = (short)f2bf(xhi.y);
        a[6] = (short)f2bf(xhi.z); a[7] = (short)f2bf(xhi.w);
        acc = __builtin_amdgcn_mfma_f32_16x16x32_bf16(a, a, acc, 0, 0, 0);
      }
#pragma unroll
      for (int r = 0; r < 4; ++r) Scr[w * 256 + r * 64 + lane] = acc[r];
    }
    __syncthreads();

    // ---- D: reduce 16 partial tiles -> Gm ----
    {
      const int o = t >> 2, q = t & 3;
      float s = Scr[q * 256 + o] + Scr[(q + 4) * 256 + o] +
                Scr[(q + 8) * 256 + o] + Scr[(q + 12) * 256 + o];
      s += __shfl_xor(s, 1);
      s += __shfl_xor(s, 2);
      if (q == 0) {
        const int p = o & 15;
        const int j = ((o >> 4) & 3) * 4 + (o >> 6);
        Gm[j][p] = s;
      }
    }
    __syncthreads();

    // ---- E: single-wave triangular solve in Gram domain (verbatim, verified) ----
    if (t < 64) {
      const int r = t & 15;
      float Lreg[PANEL];
      float rn[PANEL];
#pragma unroll
      for (int m = 0; m < PANEL; ++m) {
        const float g = Gm[r][m];
        float accL = (r == m) ? 1.0f : 0.0f;
        float nm = Gm[m][m];
#pragma unroll
        for (int j = 0; j < m; ++j) {
          float p = Lreg[j] * g;
          p += __shfl_xor(p, 1);
          p += __shfl_xor(p, 2);
          p += __shfl_xor(p, 4);
          p += __shfl_xor(p, 8);
          const float cj = p * rn[j];
          accL -= cj * Lreg[j];
          nm -= cj * p;
        }
        Lreg[m] = accL;
        rn[m] = 1.0f / nm;
        if (t == 0) rinv[i0 + m] = rn[m];
      }
      if (t < 16) {
#pragma unroll
        for (int m = 0; m < PANEL; ++m) LT[r][m] = Lreg[m];
      }
    }
    __syncthreads();

    // ---- F: gemm3 Q_panel = L * X_panel (fp32) -> global + csum partials ----
    {
      const int m0 = (t >> 8) << 2;
      const int dg = (t & 255) << 2;
      float4 a0 = {0.f,0.f,0.f,0.f}, a1 = {0.f,0.f,0.f,0.f};
      float4 a2 = {0.f,0.f,0.f,0.f}, a3 = {0.f,0.f,0.f,0.f};
#pragma unroll
      for (int r = 0; r < PANEL; ++r) {
        const float4 xv = *(const float4*)&Xc[r][dg];
        const float4 lt = *(const float4*)&LT[r][m0];     // wave-uniform broadcast
        a0.x += lt.x * xv.x; a0.y += lt.x * xv.y; a0.z += lt.x * xv.z; a0.w += lt.x * xv.w;
        a1.x += lt.y * xv.x; a1.y += lt.y * xv.y; a1.z += lt.y * xv.z; a1.w += lt.y * xv.w;
        a2.x += lt.z * xv.x; a2.y += lt.z * xv.y; a2.z += lt.z * xv.z; a2.w += lt.z * xv.w;
        a3.x += lt.w * xv.x; a3.y += lt.w * xv.y; a3.z += lt.w * xv.z; a3.w += lt.w * xv.w;
      }
      *(float4*)(qg + (size_t)(i0 + m0 + 0) * D + dg) = a0;
      *(float4*)(qg + (size_t)(i0 + m0 + 1) * D + dg) = a1;
      *(float4*)(qg + (size_t)(i0 + m0 + 2) * D + dg) = a2;
      *(float4*)(qg + (size_t)(i0 + m0 + 3) * D + dg) = a3;
      float4 ps;
      ps.x = a0.x*a0.x + a1.x*a1.x + a2.x*a2.x + a3.x*a3.x;
      ps.y = a0.y*a0.y + a1.y*a1.y + a2.y*a2.y + a3.y*a3.y;
      ps.z = a0.z*a0.z + a1.z*a1.z + a2.z*a2.z + a3.z*a3.z;
      ps.w = a0.w*a0.w + a1.w*a1.w + a2.w*a2.w + a3.w*a3.w;
      *(float4*)&Scr[(t >> 8) * 1024 + dg] = ps;
    }
    __syncthreads();  // drains gemm3 stores (vmcnt(0) before s_barrier): next dots read Q safely

    // ---- G: csum + stage next X panel (Xc dead), prefetch panel k+2 ----
    csum += Scr[t] + Scr[1024 + t] + Scr[2048 + t] + Scr[3072 + t];
    if (k + 1 < NPANELS) {
#pragma unroll
      for (int r = 0; r < 4; ++r) {
        const int idx = r * 1024 + t;
        *(float4*)&Xc[idx >> 8][(idx & 255) << 2] = xr[r];
      }
      if (k + 2 < NPANELS) {
        const float4* s = (const float4*)(xg + (size_t)(k + 2) * (PANEL * D));
#pragma unroll
        for (int r = 0; r < 4; ++r) xr[r] = s[r * 1024 + t];
      }
    }
    __syncthreads();
  }

  // ---- final column-wise normalization, float4-vectorized ----
  Scr[t] = 1.0f / sqrtf(csum);
  __syncthreads();
  {
    float4* qv = (float4*)qg;
#pragma unroll 4
    for (int i = 0; i < 32; ++i) {
      const int f = i * 1024 + t;
      const float4 inv4 = *(const float4*)&Scr[(f & 255) << 2];
      float4 v = qv[f];
      v.x *= inv4.x; v.y *= inv4.y; v.z *= inv4.z; v.w *= inv4.w;
      qv[f] = v;
    }
  }
}

extern "C" void kernel_launch(void* const* d_in, const int* in_sizes, int n_in,
                              void* d_out, int out_size, void* d_ws, size_t ws_size,
                              hipStream_t stream) {
  const float* x = (const float*)d_in[0];
  float* out = (float*)d_out;
  gs_kernel<<<dim3(256), dim3(NTHREADS), 0, stream>>>(x, out);
}

// Round 3
// 561.719 us; speedup vs baseline: 1.1322x; 1.1322x over previous
//
#include <hip/hip_runtime.h>
#include <math.h>

#define D 1024
#define NROW 128
#define PANEL 16
#define NPANELS 8
#define NTHREADS 1024
#define XP 1028                       // Xc row pitch (floats): +16B rotates banks per row
#define XBP 1032                      // Xb row pitch (ushorts): 2064B/row, 16B-aligned, rotates banks
#define MAXPREV ((NPANELS - 1) * PANEL)

typedef __attribute__((ext_vector_type(8))) short short8;
typedef __attribute__((ext_vector_type(4))) float floatx4;

__device__ __forceinline__ unsigned short f2bf(float f) {  // RNE f32 -> bf16 (inputs finite)
  unsigned int u = __builtin_bit_cast(unsigned int, f);
  u += 0x7fffu + ((u >> 16) & 1u);
  return (unsigned short)(u >> 16);
}
__device__ __forceinline__ float bf2f(unsigned short s) {
  return __builtin_bit_cast(float, ((unsigned int)s) << 16);
}

// Classical block Gram-Schmidt (reference projects ORIGINAL x_i onto previous q_j).
// WS=true: Q re-reads come from a bf16 workspace mirror (half traffic, no f2bf in dots);
//          normalization deferred to a separate streaming kernel via csum in ws.
// WS=false: self-contained fallback (round-2 behavior) if workspace is too small.
template <bool WS>
__global__ __launch_bounds__(NTHREADS, 4) void gs_kernel(const float* __restrict__ xg_all,
                                                         float* __restrict__ qg_all,
                                                         unsigned short* __restrict__ qws_all,
                                                         float* __restrict__ cws) {
  __shared__ __align__(16) float Xc[PANEL][XP];          // 64 KB fp32 master panel (exact)
  __shared__ __align__(16) unsigned short Xb[PANEL][XBP];// 33 KB bf16 mirror (MFMA operands)
  __shared__ __align__(16) float Scr[4096];              // 16 KB MFMA partials / csum partials
  __shared__ __align__(16) float Smb[MAXPREV][16];       // 7 KB scaled S rows (all prev rows)
  __shared__ float Gm[PANEL][PANEL];
  __shared__ float LT[PANEL][PANEL];                     // LT[r][m] = L[m][r]
  __shared__ float rinv[NROW];

  const int t = threadIdx.x;
  const int lane = t & 63;
  const int w = t >> 6;
  const int wb = w << 6;               // wave-owned 64-column strip base
  const size_t off = (size_t)blockIdx.x * (NROW * D);
  const float* xg = xg_all + off;
  float* qg = qg_all + off;
  unsigned short* qws = WS ? (qws_all + off) : nullptr;

  float csum = 0.0f;   // column t sum of squares
  float4 xr[4];        // X-panel register prefetch

  // ---- prologue: stage panel 0 into Xc + Xb, prefetch panel 1 ----
  {
    const float4* s = (const float4*)xg;
#pragma unroll
    for (int r = 0; r < 4; ++r) xr[r] = s[r * 1024 + t];
#pragma unroll
    for (int r = 0; r < 4; ++r) {
      const int idx = r * 1024 + t;
      *(float4*)&Xc[idx >> 8][(idx & 255) << 2] = xr[r];
      ushort4 ub;
      ub.x = f2bf(xr[r].x); ub.y = f2bf(xr[r].y); ub.z = f2bf(xr[r].z); ub.w = f2bf(xr[r].w);
      *(ushort4*)&Xb[idx >> 8][(idx & 255) << 2] = ub;
    }
    const float4* s1 = (const float4*)(xg + PANEL * D);
#pragma unroll
    for (int r = 0; r < 4; ++r) xr[r] = s1[r * 1024 + t];
  }
  __syncthreads();

  for (int k = 0; k < NPANELS; ++k) {
    const int i0 = k * PANEL;

    // ---- A: dots. Wave w < k computes S_w = Q_w * X_k^T (16x16, full K=1024). ----
    if (w < k) {
      const int m = lane & 15;    // Q row within chunk / X row within panel
      const int kb = lane >> 4;   // K sub-block
      floatx4 acc = {0.f, 0.f, 0.f, 0.f};
      if constexpr (WS) {
        const unsigned short* qrow = qws + (size_t)(w * PANEL + m) * D;
#pragma unroll
        for (int sb = 0; sb < 4; ++sb) {
          short8 af[8];
#pragma unroll
          for (int u = 0; u < 8; ++u)
            af[u] = *(const short8*)(qrow + (sb * 8 + u) * 32 + kb * 8);
#pragma unroll
          for (int u = 0; u < 8; ++u) {
            const int kk = (sb * 8 + u) * 32 + kb * 8;
            const short8 b = *(const short8*)&Xb[m][kk];
            acc = __builtin_amdgcn_mfma_f32_16x16x32_bf16(af[u], b, acc, 0, 0, 0);
          }
        }
      } else {
        const float* qrow = qg + (size_t)(w * PANEL + m) * D;
#pragma unroll 4
        for (int s = 0; s < 32; ++s) {
          const int kk = s * 32 + kb * 8;
          const float4 qlo = *(const float4*)(qrow + kk);
          const float4 qhi = *(const float4*)(qrow + kk + 4);
          short8 a;
          a[0] = (short)f2bf(qlo.x); a[1] = (short)f2bf(qlo.y);
          a[2] = (short)f2bf(qlo.z); a[3] = (short)f2bf(qlo.w);
          a[4] = (short)f2bf(qhi.x); a[5] = (short)f2bf(qhi.y);
          a[6] = (short)f2bf(qhi.z); a[7] = (short)f2bf(qhi.w);
          const short8 b = *(const short8*)&Xb[m][kk];
          acc = __builtin_amdgcn_mfma_f32_16x16x32_bf16(a, b, acc, 0, 0, 0);
        }
      }
      // C/D map: col = lane&15 (=p), row = (lane>>4)*4 + reg (=j within chunk)
#pragma unroll
      for (int r = 0; r < 4; ++r) {
        const int j = w * PANEL + kb * 4 + r;
        Smb[j][m] = acc[r] * rinv[j];
      }
    }
    __syncthreads();

    // ---- B: fp32 update X_k -= sum_j Smb[j][p] * Q[j][d]; wave-local columns. ----
    if (k > 0) {
      const int p0 = (lane >> 4) << 2;
      const int d0 = wb + ((lane & 15) << 2);
      float4 x0 = *(const float4*)&Xc[p0 + 0][d0];
      float4 x1 = *(const float4*)&Xc[p0 + 1][d0];
      float4 x2 = *(const float4*)&Xc[p0 + 2][d0];
      float4 x3 = *(const float4*)&Xc[p0 + 3][d0];
      for (int jj = 0; jj < i0; jj += 16) {   // 16-deep load batches: latency overlap
        if constexpr (WS) {
          ushort4 qb_[16];
#pragma unroll
          for (int u = 0; u < 16; ++u)
            qb_[u] = *(const ushort4*)(qws + (size_t)(jj + u) * D + d0);
#pragma unroll
          for (int u = 0; u < 16; ++u) {
            const float4 sv = *(const float4*)&Smb[jj + u][p0];  // wave-uniform broadcast
            const float q0 = bf2f(qb_[u].x), q1 = bf2f(qb_[u].y);
            const float q2 = bf2f(qb_[u].z), q3 = bf2f(qb_[u].w);
            x0.x -= sv.x * q0; x0.y -= sv.x * q1; x0.z -= sv.x * q2; x0.w -= sv.x * q3;
            x1.x -= sv.y * q0; x1.y -= sv.y * q1; x1.z -= sv.y * q2; x1.w -= sv.y * q3;
            x2.x -= sv.z * q0; x2.y -= sv.z * q1; x2.z -= sv.z * q2; x2.w -= sv.z * q3;
            x3.x -= sv.w * q0; x3.y -= sv.w * q1; x3.z -= sv.w * q2; x3.w -= sv.w * q3;
          }
        } else {
          float4 qf_[16];
#pragma unroll
          for (int u = 0; u < 16; ++u)
            qf_[u] = *(const float4*)(qg + (size_t)(jj + u) * D + d0);
#pragma unroll
          for (int u = 0; u < 16; ++u) {
            const float4 sv = *(const float4*)&Smb[jj + u][p0];
            const float4 qv = qf_[u];
            x0.x -= sv.x * qv.x; x0.y -= sv.x * qv.y; x0.z -= sv.x * qv.z; x0.w -= sv.x * qv.w;
            x1.x -= sv.y * qv.x; x1.y -= sv.y * qv.y; x1.z -= sv.y * qv.z; x1.w -= sv.y * qv.w;
            x2.x -= sv.z * qv.x; x2.y -= sv.z * qv.y; x2.z -= sv.z * qv.z; x2.w -= sv.z * qv.w;
            x3.x -= sv.w * qv.x; x3.y -= sv.w * qv.y; x3.z -= sv.w * qv.z; x3.w -= sv.w * qv.w;
          }
        }
      }
      *(float4*)&Xc[p0 + 0][d0] = x0;
      *(float4*)&Xc[p0 + 1][d0] = x1;
      *(float4*)&Xc[p0 + 2][d0] = x2;
      *(float4*)&Xc[p0 + 3][d0] = x3;
      // refresh bf16 mirror for this wave's strip (values already in registers)
      ushort4 u0, u1, u2, u3;
      u0.x = f2bf(x0.x); u0.y = f2bf(x0.y); u0.z = f2bf(x0.z); u0.w = f2bf(x0.w);
      u1.x = f2bf(x1.x); u1.y = f2bf(x1.y); u1.z = f2bf(x1.z); u1.w = f2bf(x1.w);
      u2.x = f2bf(x2.x); u2.y = f2bf(x2.y); u2.z = f2bf(x2.z); u2.w = f2bf(x2.w);
      u3.x = f2bf(x3.x); u3.y = f2bf(x3.y); u3.z = f2bf(x3.z); u3.w = f2bf(x3.w);
      *(ushort4*)&Xb[p0 + 0][d0] = u0;
      *(ushort4*)&Xb[p0 + 1][d0] = u1;
      *(ushort4*)&Xb[p0 + 2][d0] = u2;
      *(ushort4*)&Xb[p0 + 3][d0] = u3;
    }
    // no barrier: Gram reads only this wave's strip of Xb (same-wave LDS ordering)

    // ---- C: within-panel Gram via MFMA; wave w covers K in [64w, 64w+64) ----
    {
      const int m = lane & 15;
      const int kb = lane >> 4;
      floatx4 acc = {0.f, 0.f, 0.f, 0.f};
#pragma unroll
      for (int h = 0; h < 2; ++h) {
        const int kk = wb + kb * 8 + h * 32;
        const short8 a = *(const short8*)&Xb[m][kk];
        acc = __builtin_amdgcn_mfma_f32_16x16x32_bf16(a, a, acc, 0, 0, 0);
      }
#pragma unroll
      for (int r = 0; r < 4; ++r) Scr[w * 256 + r * 64 + lane] = acc[r];
    }
    __syncthreads();

    // ---- D: reduce 16 partial tiles -> Gm ----
    {
      const int o = t >> 2, q = t & 3;
      float s = Scr[q * 256 + o] + Scr[(q + 4) * 256 + o] +
                Scr[(q + 8) * 256 + o] + Scr[(q + 12) * 256 + o];
      s += __shfl_xor(s, 1);
      s += __shfl_xor(s, 2);
      if (q == 0) {
        const int p = o & 15;
        const int j = ((o >> 4) & 3) * 4 + (o >> 6);
        Gm[j][p] = s;
      }
    }
    __syncthreads();

    // ---- E: single-wave triangular solve in Gram domain (verbatim, verified) ----
    if (t < 64) {
      const int r = t & 15;
      float Lreg[PANEL];
      float rn[PANEL];
#pragma unroll
      for (int m = 0; m < PANEL; ++m) {
        const float g = Gm[r][m];
        float accL = (r == m) ? 1.0f : 0.0f;
        float nm = Gm[m][m];
#pragma unroll
        for (int j = 0; j < m; ++j) {
          float p = Lreg[j] * g;
          p += __shfl_xor(p, 1);
          p += __shfl_xor(p, 2);
          p += __shfl_xor(p, 4);
          p += __shfl_xor(p, 8);
          const float cj = p * rn[j];
          accL -= cj * Lreg[j];
          nm -= cj * p;
        }
        Lreg[m] = accL;
        rn[m] = 1.0f / nm;
        if (t == 0) rinv[i0 + m] = rn[m];
      }
      if (t < 16) {
#pragma unroll
        for (int m = 0; m < PANEL; ++m) LT[r][m] = Lreg[m];
      }
    }
    __syncthreads();

    // ---- F: gemm3 Q_panel = L * X_panel (fp32) -> global fp32 (+bf16 ws) + csum partials ----
    {
      const int m0 = (t >> 8) << 2;
      const int dg = (t & 255) << 2;
      float4 a0 = {0.f,0.f,0.f,0.f}, a1 = {0.f,0.f,0.f,0.f};
      float4 a2 = {0.f,0.f,0.f,0.f}, a3 = {0.f,0.f,0.f,0.f};
#pragma unroll
      for (int r = 0; r < PANEL; ++r) {
        const float4 xv = *(const float4*)&Xc[r][dg];
        const float4 lt = *(const float4*)&LT[r][m0];     // wave-uniform broadcast
        a0.x += lt.x * xv.x; a0.y += lt.x * xv.y; a0.z += lt.x * xv.z; a0.w += lt.x * xv.w;
        a1.x += lt.y * xv.x; a1.y += lt.y * xv.y; a1.z += lt.y * xv.z; a1.w += lt.y * xv.w;
        a2.x += lt.z * xv.x; a2.y += lt.z * xv.y; a2.z += lt.z * xv.z; a2.w += lt.z * xv.w;
        a3.x += lt.w * xv.x; a3.y += lt.w * xv.y; a3.z += lt.w * xv.z; a3.w += lt.w * xv.w;
      }
      *(float4*)(qg + (size_t)(i0 + m0 + 0) * D + dg) = a0;
      *(float4*)(qg + (size_t)(i0 + m0 + 1) * D + dg) = a1;
      *(float4*)(qg + (size_t)(i0 + m0 + 2) * D + dg) = a2;
      *(float4*)(qg + (size_t)(i0 + m0 + 3) * D + dg) = a3;
      if constexpr (WS) {
        ushort4 u0, u1, u2, u3;
        u0.x = f2bf(a0.x); u0.y = f2bf(a0.y); u0.z = f2bf(a0.z); u0.w = f2bf(a0.w);
        u1.x = f2bf(a1.x); u1.y = f2bf(a1.y); u1.z = f2bf(a1.z); u1.w = f2bf(a1.w);
        u2.x = f2bf(a2.x); u2.y = f2bf(a2.y); u2.z = f2bf(a2.z); u2.w = f2bf(a2.w);
        u3.x = f2bf(a3.x); u3.y = f2bf(a3.y); u3.z = f2bf(a3.z); u3.w = f2bf(a3.w);
        *(ushort4*)(qws + (size_t)(i0 + m0 + 0) * D + dg) = u0;
        *(ushort4*)(qws + (size_t)(i0 + m0 + 1) * D + dg) = u1;
        *(ushort4*)(qws + (size_t)(i0 + m0 + 2) * D + dg) = u2;
        *(ushort4*)(qws + (size_t)(i0 + m0 + 3) * D + dg) = u3;
      }
      float4 ps;
      ps.x = a0.x*a0.x + a1.x*a1.x + a2.x*a2.x + a3.x*a3.x;
      ps.y = a0.y*a0.y + a1.y*a1.y + a2.y*a2.y + a3.y*a3.y;
      ps.z = a0.z*a0.z + a1.z*a1.z + a2.z*a2.z + a3.z*a3.z;
      ps.w = a0.w*a0.w + a1.w*a1.w + a2.w*a2.w + a3.w*a3.w;
      *(float4*)&Scr[(t >> 8) * 1024 + dg] = ps;
    }
    __syncthreads();  // drains gemm3 stores (vmcnt(0) before s_barrier): next dots read Q safely

    // ---- G: csum + stage next X panel (Xc+Xb dead), prefetch panel k+2 ----
    csum += Scr[t] + Scr[1024 + t] + Scr[2048 + t] + Scr[3072 + t];
    if (k + 1 < NPANELS) {
#pragma unroll
      for (int r = 0; r < 4; ++r) {
        const int idx = r * 1024 + t;
        *(float4*)&Xc[idx >> 8][(idx & 255) << 2] = xr[r];
        ushort4 ub;
        ub.x = f2bf(xr[r].x); ub.y = f2bf(xr[r].y); ub.z = f2bf(xr[r].z); ub.w = f2bf(xr[r].w);
        *(ushort4*)&Xb[idx >> 8][(idx & 255) << 2] = ub;
      }
      if (k + 2 < NPANELS) {
        const float4* s = (const float4*)(xg + (size_t)(k + 2) * (PANEL * D));
#pragma unroll
        for (int r = 0; r < 4; ++r) xr[r] = s[r * 1024 + t];
      }
    }
    __syncthreads();
  }

  if constexpr (WS) {
    // csum -> workspace; normalization happens in the streaming norm_kernel
    cws[(size_t)blockIdx.x * 1024 + t] = csum;
  } else {
    // ---- in-kernel final column-wise normalization (fallback) ----
    Scr[t] = 1.0f / sqrtf(csum);
    __syncthreads();
    float4* qv = (float4*)qg;
#pragma unroll 4
    for (int i = 0; i < 32; ++i) {
      const int f = i * 1024 + t;
      const float4 inv4 = *(const float4*)&Scr[(f & 255) << 2];
      float4 v = qv[f];
      v.x *= inv4.x; v.y *= inv4.y; v.z *= inv4.z; v.w *= inv4.w;
      qv[f] = v;
    }
  }
}

// Streaming column-normalization: full-grid occupancy, pure BW.
__global__ __launch_bounds__(256) void norm_kernel(float* __restrict__ qg_all,
                                                   const float* __restrict__ cws) {
  const int bc = blockIdx.x >> 3;          // which (b,c) matrix
  const int o = blockIdx.x & 7;            // row-group [16o, 16o+16)
  const int t = threadIdx.x;
  const float4 c4 = *(const float4*)&cws[(size_t)bc * 1024 + t * 4];
  float4 inv4;
  inv4.x = 1.0f / sqrtf(c4.x); inv4.y = 1.0f / sqrtf(c4.y);
  inv4.z = 1.0f / sqrtf(c4.z); inv4.w = 1.0f / sqrtf(c4.w);
  float4* qv = (float4*)(qg_all + (size_t)bc * (NROW * D) + (size_t)o * 16 * D);
#pragma unroll 8
  for (int r = 0; r < 16; ++r) {
    float4 v = qv[r * 256 + t];
    v.x *= inv4.x; v.y *= inv4.y; v.z *= inv4.z; v.w *= inv4.w;
    qv[r * 256 + t] = v;
  }
}

extern "C" void kernel_launch(void* const* d_in, const int* in_sizes, int n_in,
                              void* d_out, int out_size, void* d_ws, size_t ws_size,
                              hipStream_t stream) {
  const float* x = (const float*)d_in[0];
  float* out = (float*)d_out;
  const size_t qws_bytes = (size_t)256 * NROW * D * sizeof(unsigned short);  // 67 MB
  const size_t need = qws_bytes + (size_t)256 * D * sizeof(float);           // + 1 MB csum
  if (d_ws != nullptr && ws_size >= need) {
    unsigned short* qws = (unsigned short*)d_ws;
    float* cws = (float*)((char*)d_ws + qws_bytes);
    gs_kernel<true><<<dim3(256), dim3(NTHREADS), 0, stream>>>(x, out, qws, cws);
    norm_kernel<<<dim3(2048), dim3(256), 0, stream>>>(out, cws);
  } else {
    gs_kernel<false><<<dim3(256), dim3(NTHREADS), 0, stream>>>(x, out, nullptr, nullptr);
  }
}

// Round 4
// 410.796 us; speedup vs baseline: 1.5482x; 1.3674x over previous
//
#include <hip/hip_runtime.h>
#include <math.h>

#define D 1024
#define NROW 128
#define PANEL 16
#define NPANELS 8
#define NTHREADS 1024
#define GP 132     // G/T pitch (floats): 528 B rows, 16B-aligned, 4-bank rotation
#define XSP 136    // Xs/XT/Tb pitch (ushorts): 272 B rows, 16B-aligned
#define WPITCH 17
#define RPITCH 132

// LDS region byte offsets (overlays: lifetimes are disjoint, see comments)
#define R1_OFF 67584
#define R2_OFF 135168
#define SMEM_BYTES (R2_OFF + 18944)

typedef __attribute__((ext_vector_type(8))) short short8;
typedef __attribute__((ext_vector_type(4))) float floatx4;

__device__ __forceinline__ unsigned short f2bf(float f) {  // RNE f32 -> bf16 (inputs finite)
  unsigned int u = __builtin_bit_cast(unsigned int, f);
  u += 0x7fffu + ((u >> 16) & 1u);
  return (unsigned short)(u >> 16);
}

// Full Gram-domain classical block Gram-Schmidt.
//   Phase G : G = X·X^T via bf16 MFMA, K-sliced (X read ONCE from HBM).
//   Solve   : per panel, entirely in LDS:  W = T·G (dots vs original X),
//             Gm = G_kk - sum_j rinv_j W_j W_j^T (residual panel Gram),
//             16x16 Gram-domain solve (verbatim, verified), T_panel = L·(E - C^T·T).
//   Phase TX: Q = T·X via bf16 MFMA per 128-column block; per-column csum completes
//             in-block -> normalize IN REGISTERS before the single Q write.
__global__ __launch_bounds__(NTHREADS, 4) void gs_kernel(const float* __restrict__ xg_all,
                                                         float* __restrict__ qg_all) {
  __shared__ __align__(16) char smem[SMEM_BYTES];
  // region0: G (solve) <-> XT (TX staging)
  float (*G)[GP] = (float(*)[GP])(smem);
  unsigned short (*XT)[XSP] = (unsigned short(*)[XSP])(smem);
  // region1: Xs (G staging) <-> T fp32 (solve) <-> Tb bf16 (TX; converted via reg round-trip)
  float (*T)[GP] = (float(*)[GP])(smem + R1_OFF);
  unsigned short (*Xs)[XSP] = (unsigned short(*)[XSP])(smem + R1_OFF);
  unsigned short (*Tb)[XSP] = (unsigned short(*)[XSP])(smem + R1_OFF);
  // region2: W+R (solve) <-> Scr (TX csum, pitch 33, spills into dead Gm area)
  float (*W)[WPITCH] = (float(*)[WPITCH])(smem + R2_OFF);
  float (*R)[RPITCH] = (float(*)[RPITCH])(smem + R2_OFF + 7616);
  float* Scr = (float*)(smem + R2_OFF);
  float (*Gm)[16] = (float(*)[16])(smem + R2_OFF + 16384);
  float (*LT)[16] = (float(*)[16])(smem + R2_OFF + 17408);  // LT[r][m] = L[m][r]
  float* rinv = (float*)(smem + R2_OFF + 18432);  // solve: 1/||q||^2 ; TX: column inv-norms

  const int t = threadIdx.x;
  const int lane = t & 63;
  const int w = t >> 6;
  const int m = lane & 15;
  const int kb = lane >> 4;
  const size_t off = (size_t)blockIdx.x * (NROW * D);
  const float* xg = xg_all + off;
  float* qg = qg_all + off;

  // ================= Phase G: G = X X^T, K-sliced (8 slices of 128) =================
  // 36 lower-triangle 16x16 tiles; wave w owns tiles {w, w+16, w+32(<36)}, accumulators
  // live in registers across slices (no LDS RMW).
  int ti0, tj0, ti1, tj1, ti2 = 0, tj2 = 0;
  {
    int id = w, ti = 0;
    while ((ti + 1) * (ti + 2) / 2 <= id) ++ti;
    ti0 = ti; tj0 = id - ti * (ti + 1) / 2;
    id = w + 16; ti = 0;
    while ((ti + 1) * (ti + 2) / 2 <= id) ++ti;
    ti1 = ti; tj1 = id - ti * (ti + 1) / 2;
    if (w < 4) {
      id = w + 32; ti = 0;
      while ((ti + 1) * (ti + 2) / 2 <= id) ++ti;
      ti2 = ti; tj2 = id - ti * (ti + 1) / 2;
    }
  }
  floatx4 ga0 = {0.f, 0.f, 0.f, 0.f}, ga1 = {0.f, 0.f, 0.f, 0.f}, ga2 = {0.f, 0.f, 0.f, 0.f};

#define GFRAG(TI, TJ, ACC) do { \
    _Pragma("unroll") \
    for (int s4 = 0; s4 < 4; ++s4) { \
      const int kk = s4 * 32 + kb * 8; \
      const short8 a_ = *(const short8*)&Xs[(TI) * 16 + m][kk]; \
      const short8 b_ = *(const short8*)&Xs[(TJ) * 16 + m][kk]; \
      ACC = __builtin_amdgcn_mfma_f32_16x16x32_bf16(a_, b_, ACC, 0, 0, 0); \
    } } while (0)

  for (int ks = 0; ks < 8; ++ks) {
    // stage K-slice: all 128 rows, cols [128ks, 128ks+128), fp32 -> bf16
#pragma unroll
    for (int qi = 0; qi < 4; ++qi) {
      const int idx = qi * 1024 + t;
      const int row = idx >> 5;
      const int c4 = (idx & 31) << 2;
      const float4 v = *(const float4*)(xg + (size_t)row * D + ks * 128 + c4);
      ushort4 u;
      u.x = f2bf(v.x); u.y = f2bf(v.y); u.z = f2bf(v.z); u.w = f2bf(v.w);
      *(ushort4*)&Xs[row][c4] = u;
    }
    __syncthreads();
    GFRAG(ti0, tj0, ga0);
    GFRAG(ti1, tj1, ga1);
    if (w < 4) GFRAG(ti2, tj2, ga2);
    __syncthreads();  // frag reads done before next slice overwrites Xs
  }
  // write G (+ symmetric mirror); C/D map: row=(lane>>4)*4+r, col=lane&15
#define GWRITE(TI, TJ, ACC) do { \
    _Pragma("unroll") \
    for (int r = 0; r < 4; ++r) { \
      const int gr = (TI) * 16 + kb * 4 + r, gc = (TJ) * 16 + m; \
      G[gr][gc] = ACC[r]; \
      if ((TI) != (TJ)) G[gc][gr] = ACC[r]; \
    } } while (0)
  GWRITE(ti0, tj0, ga0);
  GWRITE(ti1, tj1, ga1);
  if (w < 4) GWRITE(ti2, tj2, ga2);
  __syncthreads();

  // ================= Solve: 8 panels, all in LDS =================
  for (int k = 0; k < NPANELS; ++k) {
    const int i0 = k * PANEL;

    // ---- W[j][p] = q_j · x_{i0+p} = sum_{mm<=j} T[j][mm] * G[mm][i0+p], j < i0 ----
    if (k > 0) {
#pragma unroll
      for (int jb = 0; jb < 2; ++jb) {
        const int j = jb * 64 + (t >> 4);
        if (j < i0) {
          const int p = t & 15;
          float s = 0.f;
          for (int mm = 0; mm <= j; ++mm)  // T[j][mm]=0 beyond j
            s += T[j][mm] * G[mm][i0 + p];
          W[j][p] = s;
        }
      }
    }
    __syncthreads();

    // ---- R = E_panel - C^T·T_prev (all threads) ; Gm (t<256) ----
    {
      const int col = t & 127;
      const int m8 = t >> 7;
      const int jst = (w & 1) << 6;  // T[j][col]=0 for j<col; col >= (w&1)*64 wave-uniform
#pragma unroll
      for (int h = 0; h < 2; ++h) {
        const int mm = m8 + 8 * h;
        float r = (col == i0 + mm) ? 1.0f : 0.0f;
        for (int j = jst; j < i0; ++j)
          r -= (W[j][mm] * rinv[j]) * T[j][col];
        R[mm][col] = r;
      }
    }
    if (t < 256) {
      const int p = t >> 4, q = t & 15;
      float s = G[i0 + p][i0 + q];
      for (int j = 0; j < i0; ++j)
        s -= rinv[j] * W[j][p] * W[j][q];
      Gm[p][q] = s;
    }
    __syncthreads();

    // ---- single-wave 16x16 triangular solve in Gram domain (verbatim, verified) ----
    if (t < 64) {
      const int r = t & 15;
      float Lreg[PANEL];
      float rn[PANEL];
#pragma unroll
      for (int mq = 0; mq < PANEL; ++mq) {
        const float g = Gm[r][mq];
        float accL = (r == mq) ? 1.0f : 0.0f;
        float nm = Gm[mq][mq];
#pragma unroll
        for (int j = 0; j < mq; ++j) {
          float p = Lreg[j] * g;
          p += __shfl_xor(p, 1);
          p += __shfl_xor(p, 2);
          p += __shfl_xor(p, 4);
          p += __shfl_xor(p, 8);
          const float cj = p * rn[j];
          accL -= cj * Lreg[j];
          nm -= cj * p;
        }
        Lreg[mq] = accL;
        rn[mq] = 1.0f / nm;
        if (t == 0) rinv[i0 + mq] = rn[mq];
      }
      if (t < 16) {
#pragma unroll
        for (int mq = 0; mq < PANEL; ++mq) LT[r][mq] = Lreg[mq];
      }
    }
    __syncthreads();

    // ---- T_panel = L · R ----
    {
      const int col = t & 127;
      const int i8 = t >> 7;
#pragma unroll
      for (int h = 0; h < 2; ++h) {
        const int ii = i8 + 8 * h;
        float s = 0.f;
#pragma unroll
        for (int mm = 0; mm < PANEL; ++mm)
          s += LT[mm][ii] * R[mm][col];
        T[i0 + ii][col] = s;
      }
    }
    __syncthreads();
  }

  // ================= Phase TX: Q = T·X (bf16 MFMA, K=128), normalize in-register =====
  // Convert T fp32 -> Tb bf16 in place (register round-trip, barrier-separated).
  {
    float tvv[16];
#pragma unroll
    for (int i = 0; i < 16; ++i) {
      const int idx = (i << 10) + t;
      tvv[i] = T[idx >> 7][idx & 127];
    }
    __syncthreads();
#pragma unroll
    for (int i = 0; i < 16; ++i) {
      const int idx = (i << 10) + t;
      Tb[idx >> 7][idx & 127] = f2bf(tvv[i]);
    }
  }

  const int tro = w >> 1;          // output tile-row (8)
  const int tch = (w & 1) << 2;    // output tile-col base (tco = tch + s, s<4)

#define TXSQ(S, QA) \
    Scr[((tch + (S)) * 16 + m) * 33 + tro * 4 + kb] = \
        QA[0] * QA[0] + QA[1] * QA[1] + QA[2] * QA[2] + QA[3] * QA[3];
#define TXST(S, QA) do { \
    const int gc_ = cb * 128 + (tch + (S)) * 16 + m; \
    const float iv_ = rinv[(tch + (S)) * 16 + m]; \
    _Pragma("unroll") \
    for (int r = 0; r < 4; ++r) \
      qg[(size_t)(tro * 16 + kb * 4 + r) * D + gc_] = QA[r] * iv_; \
  } while (0)

  for (int cb = 0; cb < 8; ++cb) {
    __syncthreads();  // prior cb's XT reads / Scr reads done (cb=0: solve+Tb done)
    // stage XT = X[:, cb*128 ...]^T as bf16 (cols become rows for the B-operand)
#pragma unroll
    for (int i = 0; i < 4; ++i) {
      const int r = i * 32 + (t >> 5);
      const int c4 = (t & 31) << 2;
      const float4 v = *(const float4*)(xg + (size_t)r * D + cb * 128 + c4);
      XT[c4 + 0][r] = f2bf(v.x);
      XT[c4 + 1][r] = f2bf(v.y);
      XT[c4 + 2][r] = f2bf(v.z);
      XT[c4 + 3][r] = f2bf(v.w);
    }
    __syncthreads();
    // 4 output tiles per wave: (tro, tch..tch+3), K=128 in 4 MFMAs, A-frag shared
    floatx4 qa0 = {0.f, 0.f, 0.f, 0.f}, qa1 = {0.f, 0.f, 0.f, 0.f};
    floatx4 qa2 = {0.f, 0.f, 0.f, 0.f}, qa3 = {0.f, 0.f, 0.f, 0.f};
#pragma unroll
    for (int s4 = 0; s4 < 4; ++s4) {
      const int kk = s4 * 32 + kb * 8;
      const short8 a = *(const short8*)&Tb[tro * 16 + m][kk];
      const short8 b0 = *(const short8*)&XT[(tch + 0) * 16 + m][kk];
      const short8 b1 = *(const short8*)&XT[(tch + 1) * 16 + m][kk];
      const short8 b2 = *(const short8*)&XT[(tch + 2) * 16 + m][kk];
      const short8 b3 = *(const short8*)&XT[(tch + 3) * 16 + m][kk];
      qa0 = __builtin_amdgcn_mfma_f32_16x16x32_bf16(a, b0, qa0, 0, 0, 0);
      qa1 = __builtin_amdgcn_mfma_f32_16x16x32_bf16(a, b1, qa1, 0, 0, 0);
      qa2 = __builtin_amdgcn_mfma_f32_16x16x32_bf16(a, b2, qa2, 0, 0, 0);
      qa3 = __builtin_amdgcn_mfma_f32_16x16x32_bf16(a, b3, qa3, 0, 0, 0);
    }
    // per-column sum of squares: 32 contributors (8 tile-rows x 4 row-groups) per column
    TXSQ(0, qa0); TXSQ(1, qa1); TXSQ(2, qa2); TXSQ(3, qa3);
    __syncthreads();
    if (t < 128) {
      float ssum = 0.f;
#pragma unroll
      for (int i = 0; i < 32; ++i) ssum += Scr[t * 33 + i];
      rinv[t] = 1.0f / sqrtf(ssum);  // column inv-norm for this cb
    }
    __syncthreads();
    // normalize in-register and write Q exactly once
    TXST(0, qa0); TXST(1, qa1); TXST(2, qa2); TXST(3, qa3);
  }
}

extern "C" void kernel_launch(void* const* d_in, const int* in_sizes, int n_in,
                              void* d_out, int out_size, void* d_ws, size_t ws_size,
                              hipStream_t stream) {
  const float* x = (const float*)d_in[0];
  float* out = (float*)d_out;
  gs_kernel<<<dim3(256), dim3(NTHREADS), 0, stream>>>(x, out);
}

// Round 5
// 374.697 us; speedup vs baseline: 1.6973x; 1.0963x over previous
//
#include <hip/hip_runtime.h>
#include <math.h>

#define D 1024
#define NROW 128
#define PANEL 16
#define NPANELS 8
#define NTHREADS 1024
#define GPITCH 132   // G/T/WT/R row pitch in floats (528 B, 16B-aligned)
#define XSP 136      // bf16 tile pitch in ushorts (272 B, 16B-aligned)

// LDS layout (byte offsets). Solve-phase residents:
//   G  [128][132] f32 @ 0       (67584)
//   T  [128][132] f32 @ 67584   (67584)
//   WT [16][132]  f32 @ 135168  (8448)   W^T: WT[p][j] = q_j . x_{i0+p}
//   R  [16][132]  f32 @ 143616  (8448)
//   Gm [16][16]       @ 152064, LT @ 153088, rinv @ 154112
// Phase-G overlay (G/T dead): Xs buf0 @ 0, buf1 @ 34816 (each 34816 B)
// Phase-TX overlay (G/T/WT/R dead): XT buf0 @ 0, buf1 @ 34816, Tb @ 69632,
//   Scr @ 104448 (16896 B). rinv stays live (reused for column norms).
#define T_OFF    67584
#define WT_OFF   135168
#define R_OFF    143616
#define GM_OFF   152064
#define LT_OFF   153088
#define RINV_OFF 154112
#define SMEM_BYTES 154624
#define XBUF_SZ  34816
#define TB_OFF   69632
#define SCR_OFF  104448

typedef __attribute__((ext_vector_type(8))) short short8;
typedef __attribute__((ext_vector_type(4))) float floatx4;

__device__ __forceinline__ unsigned short f2bf(float f) {  // RNE f32 -> bf16 (inputs finite)
  unsigned int u = __builtin_bit_cast(unsigned int, f);
  u += 0x7fffu + ((u >> 16) & 1u);
  return (unsigned short)(u >> 16);
}

__global__ __launch_bounds__(NTHREADS, 4) void gs_kernel(const float* __restrict__ xg_all,
                                                         float* __restrict__ qg_all) {
  __shared__ __align__(16) char smem[SMEM_BYTES];
  float (*G)[GPITCH] = (float(*)[GPITCH])(smem);
  float (*T)[GPITCH] = (float(*)[GPITCH])(smem + T_OFF);
  float (*WT)[GPITCH] = (float(*)[GPITCH])(smem + WT_OFF);
  float (*R)[GPITCH] = (float(*)[GPITCH])(smem + R_OFF);
  float (*Gm)[16] = (float(*)[16])(smem + GM_OFF);
  float (*LT)[16] = (float(*)[16])(smem + LT_OFF);   // LT[r][m] = L[m][r]
  float* rinv = (float*)(smem + RINV_OFF);
  unsigned short (*Tb)[XSP] = (unsigned short(*)[XSP])(smem + TB_OFF);
  float* Scr = (float*)(smem + SCR_OFF);

  const int t = threadIdx.x;
  const int lane = t & 63;
  const int w = t >> 6;
  const int m = lane & 15;
  const int kb = lane >> 4;
  const size_t off = (size_t)blockIdx.x * (NROW * D);
  const float* xg = xg_all + off;
  float* qg = qg_all + off;

  // ================= Phase G: G = X X^T, K-sliced, double-buffered =================
  int ti0, tj0, ti1, tj1, ti2 = 0, tj2 = 0;
  {
    int id = w, ti = 0;
    while ((ti + 1) * (ti + 2) / 2 <= id) ++ti;
    ti0 = ti; tj0 = id - ti * (ti + 1) / 2;
    id = w + 16; ti = 0;
    while ((ti + 1) * (ti + 2) / 2 <= id) ++ti;
    ti1 = ti; tj1 = id - ti * (ti + 1) / 2;
    if (w < 4) {
      id = w + 32; ti = 0;
      while ((ti + 1) * (ti + 2) / 2 <= id) ++ti;
      ti2 = ti; tj2 = id - ti * (ti + 1) / 2;
    }
  }
  floatx4 ga0 = {0.f, 0.f, 0.f, 0.f}, ga1 = {0.f, 0.f, 0.f, 0.f}, ga2 = {0.f, 0.f, 0.f, 0.f};
  float4 xr[4];

#define LDSLICE(KS) do { _Pragma("unroll") \
    for (int qi = 0; qi < 4; ++qi) { \
      const int idx = qi * 1024 + t; \
      const int row = idx >> 5; \
      const int c4 = (idx & 31) << 2; \
      xr[qi] = *(const float4*)(xg + (size_t)row * D + (KS) * 128 + c4); \
    } } while (0)
#define XCOMMIT(BB) do { _Pragma("unroll") \
    for (int qi = 0; qi < 4; ++qi) { \
      const int idx = qi * 1024 + t; \
      const int row = idx >> 5; \
      const int c4 = (idx & 31) << 2; \
      ushort4 u_; \
      u_.x = f2bf(xr[qi].x); u_.y = f2bf(xr[qi].y); \
      u_.z = f2bf(xr[qi].z); u_.w = f2bf(xr[qi].w); \
      *(ushort4*)((BB) + row * 272 + c4 * 2) = u_; \
    } } while (0)
#define GFRAG(BB, TI, TJ, ACC) do { _Pragma("unroll") \
    for (int s4 = 0; s4 < 4; ++s4) { \
      const int kk = s4 * 32 + kb * 8; \
      const short8 a_ = *(const short8*)((BB) + ((TI) * 16 + m) * 272 + kk * 2); \
      const short8 b_ = *(const short8*)((BB) + ((TJ) * 16 + m) * 272 + kk * 2); \
      ACC = __builtin_amdgcn_mfma_f32_16x16x32_bf16(a_, b_, ACC, 0, 0, 0); \
    } } while (0)

  LDSLICE(0);
  for (int ks = 0; ks < 8; ++ks) {
    char* sb = smem + (ks & 1) * XBUF_SZ;
    XCOMMIT(sb);
    if (ks < 7) LDSLICE(ks + 1);
    __syncthreads();   // commit visible; prior slice's frag reads (other buf) done
    GFRAG(sb, ti0, tj0, ga0);
    GFRAG(sb, ti1, tj1, ga1);
    if (w < 4) GFRAG(sb, ti2, tj2, ga2);
  }
  __syncthreads();     // all frag reads done before G overwrites the staging buffers
#define GWRITE(TI, TJ, ACC) do { _Pragma("unroll") \
    for (int r = 0; r < 4; ++r) { \
      const int gr = (TI) * 16 + kb * 4 + r, gc = (TJ) * 16 + m; \
      G[gr][gc] = ACC[r]; \
      if ((TI) != (TJ)) G[gc][gr] = ACC[r]; \
    } } while (0)
  GWRITE(ti0, tj0, ga0);
  GWRITE(ti1, tj1, ga1);
  if (w < 4) GWRITE(ti2, tj2, ga2);
  __syncthreads();

  // ================= Solve: 8 panels, batched LDS loops =================
  for (int k = 0; k < NPANELS; ++k) {
    const int i0 = k * PANEL;

    // ---- W: WT[p][j] = sum_mm T[j][mm] * G[i0+p][mm]  (p = wave id -> G row broadcast)
    if (k > 0) {
      const int jA = t & 63, j2 = jA + 64;
      float s1 = 0.f, s2 = 0.f;
      for (int mb = 0; mb < i0; mb += 8) {
        const float4 g0 = *(const float4*)&G[i0 + w][mb];
        const float4 g1 = *(const float4*)&G[i0 + w][mb + 4];
        const float4 a0 = *(const float4*)&T[jA][mb];
        const float4 a1 = *(const float4*)&T[jA][mb + 4];
        const float4 b0 = *(const float4*)&T[j2][mb];
        const float4 b1 = *(const float4*)&T[j2][mb + 4];
        s1 += a0.x * g0.x; s1 += a0.y * g0.y; s1 += a0.z * g0.z; s1 += a0.w * g0.w;
        s1 += a1.x * g1.x; s1 += a1.y * g1.y; s1 += a1.z * g1.z; s1 += a1.w * g1.w;
        s2 += b0.x * g0.x; s2 += b0.y * g0.y; s2 += b0.z * g0.z; s2 += b0.w * g0.w;
        s2 += b1.x * g1.x; s2 += b1.y * g1.y; s2 += b1.z * g1.z; s2 += b1.w * g1.w;
      }
      if (jA < i0) WT[w][jA] = s1;   // (garbage rows read when jA>=i0 are discarded)
      if (j2 < i0) WT[w][j2] = s2;
    }
    __syncthreads();

    // ---- R = E - C^T·T_prev (all threads) ; Gm (waves 12-15) ----
    {
      const int col = t & 127;
      const int mh = t >> 7, mh8 = mh + 8;
      float s0 = (col == i0 + mh) ? 1.0f : 0.0f;
      float s1 = (col == i0 + mh8) ? 1.0f : 0.0f;
      for (int jb = 0; jb < i0; jb += 8) {
#pragma unroll
        for (int u = 0; u < 8; ++u) {
          const int j = jb + u;
          const float tv = T[j][col];
          const float rv = rinv[j];
          s0 -= (WT[mh][j] * rv) * tv;
          s1 -= (WT[mh8][j] * rv) * tv;
        }
      }
      R[mh][col] = s0;
      R[mh8][col] = s1;
    }
    if (t >= 768) {
      const int p = (t >> 4) & 15, q = t & 15;
      float s = G[i0 + p][i0 + q];
      for (int jb = 0; jb < i0; jb += 8) {
#pragma unroll
        for (int u = 0; u < 8; ++u) {
          const int j = jb + u;
          s -= rinv[j] * WT[p][j] * WT[q][j];
        }
      }
      Gm[p][q] = s;
    }
    __syncthreads();

    // ---- single-wave 16x16 triangular solve in Gram domain (verbatim, verified) ----
    if (t < 64) {
      const int r = t & 15;
      float Lreg[PANEL];
      float rn[PANEL];
#pragma unroll
      for (int mq = 0; mq < PANEL; ++mq) {
        const float g = Gm[r][mq];
        float accL = (r == mq) ? 1.0f : 0.0f;
        float nm = Gm[mq][mq];
#pragma unroll
        for (int j = 0; j < mq; ++j) {
          float p = Lreg[j] * g;
          p += __shfl_xor(p, 1);
          p += __shfl_xor(p, 2);
          p += __shfl_xor(p, 4);
          p += __shfl_xor(p, 8);
          const float cj = p * rn[j];
          accL -= cj * Lreg[j];
          nm -= cj * p;
        }
        Lreg[mq] = accL;
        rn[mq] = 1.0f / nm;
        if (t == 0) rinv[i0 + mq] = rn[mq];
      }
      if (t < 16) {
#pragma unroll
        for (int mq = 0; mq < PANEL; ++mq) LT[r][mq] = Lreg[mq];
      }
    }
    __syncthreads();

    // ---- T_panel = L · R ----
    {
      const int col = t & 127;
      const int i8 = t >> 7;
#pragma unroll
      for (int h = 0; h < 2; ++h) {
        const int ii = i8 + 8 * h;
        float s = 0.f;
#pragma unroll
        for (int mm = 0; mm < PANEL; ++mm)
          s += LT[mm][ii] * R[mm][col];
        T[i0 + ii][col] = s;
      }
    }
    __syncthreads();
  }

  // ================= Phase TX: Q = T·X (bf16 MFMA), normalize in-register ==========
  {  // T fp32 -> Tb bf16 (register round-trip; Tb overlays dead T rows)
    float tvv[16];
#pragma unroll
    for (int i = 0; i < 16; ++i) {
      const int idx = (i << 10) + t;
      tvv[i] = T[idx >> 7][idx & 127];
    }
    __syncthreads();
#pragma unroll
    for (int i = 0; i < 16; ++i) {
      const int idx = (i << 10) + t;
      Tb[idx >> 7][idx & 127] = f2bf(tvv[i]);
    }
  }

  const int qq = t & 31;            // col-quad within 128-col block
  const int r0 = (t >> 5) << 2;     // 4-row group
  const int tro = w >> 1;           // output tile-row
  const int tch = (w & 1) << 2;     // output tile-col base
  float4 xt0, xt1, xt2, xt3;        // rows r0..r0+3, cols qq*4..+3 (next cb)
  {
    const float* s = xg + (size_t)r0 * D + qq * 4;
    xt0 = *(const float4*)(s);
    xt1 = *(const float4*)(s + D);
    xt2 = *(const float4*)(s + 2 * D);
    xt3 = *(const float4*)(s + 3 * D);
  }

  // XT element (row r, col c) stored at byte ((c*272 + (r&~3)*2) ^ (((c>>2)&7)<<4)) + (r&3)*2
#define TXSQ(S, QA) \
    Scr[((tch + (S)) * 16 + m) * 33 + tro * 4 + kb] = \
        QA[0] * QA[0] + QA[1] * QA[1] + QA[2] * QA[2] + QA[3] * QA[3];
#define TXST(S, QA) do { \
    const int gc_ = cb * 128 + (tch + (S)) * 16 + m; \
    const float iv_ = rinv[(tch + (S)) * 16 + m]; \
    _Pragma("unroll") \
    for (int r = 0; r < 4; ++r) \
      qg[(size_t)(tro * 16 + kb * 4 + r) * D + gc_] = QA[r] * iv_; \
  } while (0)

  for (int cb = 0; cb < 8; ++cb) {
    char* xb = smem + (cb & 1) * XBUF_SZ;
    {  // commit: in-thread 4x4 transpose, swizzled b64 writes (8 lanes/16B-slot = BW-bound)
      const int sw = (qq & 7) << 4;
      ushort4 c0, c1, c2, c3;
      c0.x = f2bf(xt0.x); c0.y = f2bf(xt1.x); c0.z = f2bf(xt2.x); c0.w = f2bf(xt3.x);
      c1.x = f2bf(xt0.y); c1.y = f2bf(xt1.y); c1.z = f2bf(xt2.y); c1.w = f2bf(xt3.y);
      c2.x = f2bf(xt0.z); c2.y = f2bf(xt1.z); c2.z = f2bf(xt2.z); c2.w = f2bf(xt3.z);
      c3.x = f2bf(xt0.w); c3.y = f2bf(xt1.w); c3.z = f2bf(xt2.w); c3.w = f2bf(xt3.w);
      const int cb0 = qq * 4;
      *(ushort4*)(xb + (((cb0 + 0) * 272 + r0 * 2) ^ sw)) = c0;
      *(ushort4*)(xb + (((cb0 + 1) * 272 + r0 * 2) ^ sw)) = c1;
      *(ushort4*)(xb + (((cb0 + 2) * 272 + r0 * 2) ^ sw)) = c2;
      *(ushort4*)(xb + (((cb0 + 3) * 272 + r0 * 2) ^ sw)) = c3;
    }
    if (cb < 7) {  // prefetch next block (hidden under MFMA + csum)
      const float* s = xg + (size_t)r0 * D + (cb + 1) * 128 + qq * 4;
      xt0 = *(const float4*)(s);
      xt1 = *(const float4*)(s + D);
      xt2 = *(const float4*)(s + 2 * D);
      xt3 = *(const float4*)(s + 3 * D);
    }
    __syncthreads();
    floatx4 qa0 = {0.f, 0.f, 0.f, 0.f}, qa1 = {0.f, 0.f, 0.f, 0.f};
    floatx4 qa2 = {0.f, 0.f, 0.f, 0.f}, qa3 = {0.f, 0.f, 0.f, 0.f};
#pragma unroll
    for (int s4 = 0; s4 < 4; ++s4) {
      const int kk = s4 * 32 + kb * 8;
      const short8 a = *(const short8*)((char*)Tb + (tro * 16 + m) * 272 + kk * 2);
      const int c0_ = (tch + 0) * 16 + m, c1_ = (tch + 1) * 16 + m;
      const int c2_ = (tch + 2) * 16 + m, c3_ = (tch + 3) * 16 + m;
      const short8 b0 = *(const short8*)(xb + ((c0_ * 272 + kk * 2) ^ (((c0_ >> 2) & 7) << 4)));
      const short8 b1 = *(const short8*)(xb + ((c1_ * 272 + kk * 2) ^ (((c1_ >> 2) & 7) << 4)));
      const short8 b2 = *(const short8*)(xb + ((c2_ * 272 + kk * 2) ^ (((c2_ >> 2) & 7) << 4)));
      const short8 b3 = *(const short8*)(xb + ((c3_ * 272 + kk * 2) ^ (((c3_ >> 2) & 7) << 4)));
      qa0 = __builtin_amdgcn_mfma_f32_16x16x32_bf16(a, b0, qa0, 0, 0, 0);
      qa1 = __builtin_amdgcn_mfma_f32_16x16x32_bf16(a, b1, qa1, 0, 0, 0);
      qa2 = __builtin_amdgcn_mfma_f32_16x16x32_bf16(a, b2, qa2, 0, 0, 0);
      qa3 = __builtin_amdgcn_mfma_f32_16x16x32_bf16(a, b3, qa3, 0, 0, 0);
    }
    TXSQ(0, qa0); TXSQ(1, qa1); TXSQ(2, qa2); TXSQ(3, qa3);
    __syncthreads();
    if (t < 128) {
      float ssum = 0.f;
#pragma unroll
      for (int i = 0; i < 32; ++i) ssum += Scr[t * 33 + i];
      rinv[t] = 1.0f / sqrtf(ssum);
    }
    __syncthreads();
    TXST(0, qa0); TXST(1, qa1); TXST(2, qa2); TXST(3, qa3);
  }
}

extern "C" void kernel_launch(void* const* d_in, const int* in_sizes, int n_in,
                              void* d_out, int out_size, void* d_ws, size_t ws_size,
                              hipStream_t stream) {
  const float* x = (const float*)d_in[0];
  float* out = (float*)d_out;
  gs_kernel<<<dim3(256), dim3(NTHREADS), 0, stream>>>(x, out);
}